// Round 12
// baseline (316.123 us; speedup 1.0000x reference)
//
#include <hip/hip_runtime.h>
#include <hip/hip_bf16.h>

// ---------------- problem constants ----------------
constexpr int F_C   = 32768;
constexpr int F_F   = 131072;
constexpr int N0    = 65536;    // B*F_C
constexpr int N1    = 262144;   // B*F_F
constexpr int C_IN  = 128;
constexpr int W_DIM = 512;
constexpr int K2c   = 9;
constexpr float RS512     = 0.04419417382415922f;   // 1/sqrt(512)
constexpr float ACT_GAINc = 1.4142135623730951f;    // sqrt(2)

// ---------------- workspace layout ----------------
constexpr size_t FO_S0  = 0;
constexpr size_t FO_S1  = 256;
constexpr size_t FO_ST  = 384;
constexpr size_t OFF_WM0T = 2048;                    // [2][9][64 o][128 ci] u16 = 294912 B
constexpr size_t OFF_WM1T = OFF_WM0T + 294912;       // [2][9][64 o][64 ci] u16 = 147456 B
constexpr size_t OFF_H0   = 458752;                  // bf16 h0: 65536*64*2  = 8388608
constexpr size_t OFF_HA   = OFF_H0 + (size_t)8388608;// bf16 ha: 262144*64*2 = 33554432
// yPre2 (N1*6 f32) reuses the h0 region (h0B dead after k_ha).
constexpr size_t OFF_YPRE = OFF_H0;
// xB (bf16 copy of x) overlays the haB region (dead until k_ha runs).
constexpr size_t OFF_XB   = OFF_HA;

typedef short s16x8 __attribute__((ext_vector_type(8)));
typedef float f32x4 __attribute__((ext_vector_type(4)));

// ---------------- helpers ----------------
__device__ __forceinline__ float b2f(unsigned short u) {
    union { unsigned int i; float f; } v; v.i = ((unsigned int)u) << 16; return v.f;
}
__device__ __forceinline__ unsigned short f2b(float f) {
    __hip_bfloat16 h = __float2bfloat16(f);
    return *reinterpret_cast<unsigned short*>(&h);
}
__device__ __forceinline__ float waveRedSum(float v) {
    for (int m = 32; m; m >>= 1) v += __shfl_xor(v, m, 64);
    return v;
}
__device__ __forceinline__ float actf(float v) {
    float y = (v >= 0.f) ? v : 0.2f * v;
    y *= ACT_GAINc;
    return fminf(fmaxf(y, -256.f), 256.f);
}

// ---------------- styles ----------------
__global__ __launch_bounds__(64)
void k_styles(const float* __restrict__ wsF,
              const float* __restrict__ a0w, const float* __restrict__ a0b,
              const float* __restrict__ a1w, const float* __restrict__ a1b,
              const float* __restrict__ atw, const float* __restrict__ atb,
              float* __restrict__ fr)
{
    int bid = blockIdx.x, lane = threadIdx.x;
    int bb, ii, ll, row; const float *aw, *ab; float* dst; float post = 1.f;
    if (bid < 256)      { bb = bid >> 7;             ii = bid & 127; ll = 0; aw = a0w; ab = a0b; dst = fr + FO_S0; row = 128; }
    else if (bid < 384) { int t = bid - 256; bb = t >> 6; ii = t & 63; ll = 1; aw = a1w; ab = a1b; dst = fr + FO_S1; row = 64; }
    else                { int t = bid - 384; bb = t >> 6; ii = t & 63; ll = 2; aw = atw; ab = atb; dst = fr + FO_ST; row = 64; post = 0.125f; }
    const float* wsv = wsF + (size_t)(bb * 3 + ll) * W_DIM;
    const float* awr = aw + (size_t)ii * W_DIM;
    float s = 0.f;
    for (int j = lane; j < W_DIM; j += 64) s += wsv[j] * awr[j];
    s = waveRedSum(s);
    if (lane == 0) dst[bb * row + ii] = (s * RS512 + ab[ii]) * post;
}

// ---------------- demodulated weights -> wmodT[b][k][o][ci] (bf16) ----------------
__global__ __launch_bounds__(256)
void k_wmod(const float* __restrict__ W0,
            const float* __restrict__ W1,
            const float* __restrict__ fr,
            unsigned short* __restrict__ wm0T,
            unsigned short* __restrict__ wm1T)
{
    int bo = blockIdx.x, tid = threadIdx.x;
    int b, o, CI, NE; const float* W; const float* S; unsigned short* dst;
    if (bo < 128) { b = bo >> 6; o = bo & 63; CI = 128; NE = 1152; W = W0; S = fr + FO_S0; dst = wm0T; }
    else { int t = bo - 128; b = t >> 6; o = t & 63; CI = 64; NE = 576; W = W1; S = fr + FO_S1; dst = wm1T; }
    const float* Wo = W + (size_t)o * NE;
    const float* Sb = S + (size_t)b * CI;
    float ss = 0.f;
    for (int idx = tid; idx < NE; idx += 256) {
        int i = idx / K2c;
        float p = Wo[idx] * Sb[i];
        ss += p * p;
    }
    __shared__ float red[4];
    float s = waveRedSum(ss);
    if ((tid & 63) == 0) red[tid >> 6] = s;
    __syncthreads();
    float d = rsqrtf(red[0] + red[1] + red[2] + red[3] + 1e-8f);
    for (int idx = tid; idx < NE; idx += 256) {
        int i = idx / K2c, kk = idx - i * K2c;
        dst[((size_t)(b * K2c + kk) * 64 + o) * CI + i] = f2b(Wo[idx] * Sb[i] * d);
    }
}

// ---------------- x f32 -> bf16 copy (coalesced) ----------------
__global__ __launch_bounds__(256)
void k_xcvt(const float* __restrict__ xF, unsigned short* __restrict__ xB)
{
    int i = blockIdx.x * 256 + threadIdx.x;
    float4 f = ((const float4*)xF)[i];
    union { unsigned short u[4]; uint2 v; } t;
    t.u[0] = f2b(f.x); t.u[1] = f2b(f.y); t.u[2] = f2b(f.z); t.u[3] = f2b(f.w);
    ((uint2*)xB)[i] = t.v;
}

// ---------------- layer0: 5+4 tap-group W LDS (40 KB, 4 blk/CU), A direct ----------------
__global__ __launch_bounds__(256, 4)
void k_layer0(const unsigned short* __restrict__ xB,
              const int*  __restrict__ fn0,
              const int*  __restrict__ fip0,
              const unsigned short* __restrict__ wm0T,   // [b][k][o][128] bf16
              unsigned short* __restrict__ h0B)
{
    __shared__ unsigned short W_lds[5 * 4096];   // 40960 B
    const int tid  = threadIdx.x;
    const int g0   = blockIdx.x * 256;
    const int b    = g0 / F_C;
    const int wave = tid >> 6, lane = tid & 63;
    const int lg   = lane >> 4, lr = lane & 15;
    const int wbase = g0 + wave * 64;
    const unsigned short* wtap = wm0T + (size_t)b * K2c * 64 * C_IN;

    int nbrk[4][9];
    #pragma unroll
    for (int rg = 0; rg < 4; ++rg) {
        int row = wbase + rg * 16 + lr;
        #pragma unroll
        for (int k = 0; k < 9; ++k) {
            int fn = fn0[(size_t)row * 9 + k];
            int ip = fip0[(size_t)row * 9 + k];
            nbrk[rg][k] = (!ip && fn < N0) ? fn : -1;
        }
    }

    f32x4 acc[4][4] = {};
    auto stage = [&](int tapBase, int nTaps, int h) {
        int nChunk = nTaps * 512;
        for (int idx = tid; idx < nChunk; idx += 256) {
            int tap = idx >> 9, rem = idx & 511;
            int row = rem >> 3, cc = rem & 7;
            uint4 v = *(const uint4*)(wtap + ((size_t)(tapBase + tap) * 64 + row) * C_IN + h * 64 + cc * 8);
            *(uint4*)(&W_lds[tap * 4096 + row * 64 + ((cc ^ (row & 7)) << 3)]) = v;
        }
    };
    auto computeTap = [&](int kk, int tapBase, int h) {
        s16x8 bf[2][4];
        #pragma unroll
        for (int c2 = 0; c2 < 2; ++c2)
            #pragma unroll
            for (int nt = 0; nt < 4; ++nt) {
                int row = nt * 16 + lr;
                bf[c2][nt] = *(const s16x8*)(&W_lds[(kk - tapBase) * 4096 + row * 64 + (((c2 * 4 + lg) ^ (row & 7)) << 3)]);
            }
        #pragma unroll
        for (int rg = 0; rg < 4; ++rg) {
            int nbr = nbrk[rg][kk];
            int pc  = nbr >= 0 ? nbr : 0;
            const uint4* ap = (const uint4*)(xB + (size_t)pc * C_IN) + lg;
            uint4 a0 = ap[h * 8], a1 = ap[h * 8 + 4];
            if (nbr < 0) { a0 = uint4{0,0,0,0}; a1 = uint4{0,0,0,0}; }
            s16x8 af0 = *reinterpret_cast<const s16x8*>(&a0);
            s16x8 af1 = *reinterpret_cast<const s16x8*>(&a1);
            #pragma unroll
            for (int nt = 0; nt < 4; ++nt)
                acc[rg][nt] = __builtin_amdgcn_mfma_f32_16x16x32_bf16(af0, bf[0][nt], acc[rg][nt], 0, 0, 0);
            #pragma unroll
            for (int nt = 0; nt < 4; ++nt)
                acc[rg][nt] = __builtin_amdgcn_mfma_f32_16x16x32_bf16(af1, bf[1][nt], acc[rg][nt], 0, 0, 0);
        }
    };

    for (int h = 0; h < 2; ++h) {
        __syncthreads();
        stage(0, 5, h);
        __syncthreads();
        for (int kk = 0; kk < 5; ++kk) computeTap(kk, 0, h);
        __syncthreads();
        stage(5, 4, h);
        __syncthreads();
        for (int kk = 5; kk < 9; ++kk) computeTap(kk, 5, h);
    }

    #pragma unroll
    for (int rg = 0; rg < 4; ++rg)
        #pragma unroll
        for (int nt = 0; nt < 4; ++nt) {
            int o = nt * 16 + lr;
            #pragma unroll
            for (int r = 0; r < 4; ++r) {
                int node = wbase + rg * 16 + lg * 4 + r;
                h0B[(size_t)node * 64 + o] = f2b(acc[rg][nt][r]);
            }
        }
}

// ---------------- smooth upsample + noise + bias + act -> ha ----------------
__global__ __launch_bounds__(256)
void k_ha(const unsigned short* __restrict__ h0B,
          const int*  __restrict__ fn1,
          const int*  __restrict__ fip1,
          const int*  __restrict__ pool,
          const float* __restrict__ nc0,
          const float* __restrict__ ns0,
          const float* __restrict__ b0,
          unsigned short* __restrict__ haB)
{
    __shared__ int   pmArr[288];
    __shared__ int   vArr[288];
    __shared__ float invCnt[32];
    const int tid = threadIdx.x;
    const int n0  = blockIdx.x * 32;
    for (int idx = tid; idx < 288; idx += 256) {
        int fn = fn1[(size_t)n0 * K2c + idx];
        int ip = fip1[(size_t)n0 * K2c + idx];
        int v  = !ip;
        int pm = -1;
        if (v && fn < N1) pm = pool[fn];
        pmArr[idx] = pm;
        vArr[idx]  = v;
    }
    __syncthreads();
    if (tid < 32) {
        int c = 0;
        #pragma unroll
        for (int k = 0; k < K2c; ++k) c += vArr[tid * K2c + k];
        invCnt[tid] = 1.f / (float)(c > 0 ? c : 1);
    }
    __syncthreads();
    const int wave = tid >> 6, lane = tid & 63;
    const float nsc  = ns0[0];
    const float bias = b0[lane];
    for (int jj = 0; jj < 8; ++jj) {
        int node = wave * 8 + jj;
        int g    = n0 + node;
        float acc = 0.f;
        #pragma unroll
        for (int k = 0; k < K2c; ++k) {
            int pm = pmArr[node * K2c + k];
            int pc = pm >= 0 ? pm : 0;
            float val = b2f(h0B[(size_t)pc * 64 + lane]);
            acc += (pm >= 0) ? val : 0.f;
        }
        float hu = acc * invCnt[node];
        float v  = hu + nc0[g & (F_F - 1)] * nsc + bias;
        haB[(size_t)g * 64 + lane] = f2b(actf(v));
    }
}

// ---------------- layer1: 256-thread block, 5+4 tap-group W LDS (40 KB, 4 blk/CU) ----------------
__global__ __launch_bounds__(256, 4)
void k_layer1(const unsigned short* __restrict__ haB,
              const int*  __restrict__ fn1,
              const int*  __restrict__ fip1,
              const unsigned short* __restrict__ wm1T,   // [b][k][o][64] bf16
              const float* __restrict__ nc1,
              const float* __restrict__ ns1,
              const float* __restrict__ b1,
              const float* __restrict__ stS,     // [2][64], already * 1/sqrt(64)
              const float* __restrict__ WtF,     // [3][64]
              float* __restrict__ hOut,
              float* __restrict__ yPre2)         // [N1][2][3]
{
    __shared__ unsigned short W_lds[5 * 4096];   // 40960 B
    const int tid  = threadIdx.x;
    const int g0   = blockIdx.x * 256;
    const int b    = g0 / F_F;
    const int wave = tid >> 6, lane = tid & 63;
    const int lg   = lane >> 4, lr = lane & 15;
    const int wbase = g0 + wave * 64;
    const unsigned short* wtap = wm1T + (size_t)b * K2c * 4096;

    int nbrk[4][9];
    #pragma unroll
    for (int rg = 0; rg < 4; ++rg) {
        int row = wbase + rg * 16 + lr;
        #pragma unroll
        for (int k = 0; k < 9; ++k) {
            int fn = fn1[(size_t)row * 9 + k];
            int ip = fip1[(size_t)row * 9 + k];
            nbrk[rg][k] = (!ip && fn < N1) ? fn : -1;
        }
    }

    f32x4 acc[4][4] = {};
    auto stage = [&](int tapBase, int nTaps) {
        int nChunk = nTaps * 512;
        for (int idx = tid; idx < nChunk; idx += 256) {
            int tap = idx >> 9, rem = idx & 511;
            int row = rem >> 3, c = rem & 7;
            uint4 v = ((const uint4*)(wtap + (size_t)tapBase * 4096))[idx];
            *(uint4*)(&W_lds[tap * 4096 + row * 64 + ((c ^ (row & 7)) << 3)]) = v;
        }
    };
    auto computeTap = [&](int kk, int tapBase) {
        s16x8 bf[2][4];
        #pragma unroll
        for (int h = 0; h < 2; ++h)
            #pragma unroll
            for (int nt = 0; nt < 4; ++nt) {
                int row = nt * 16 + lr;
                bf[h][nt] = *(const s16x8*)(&W_lds[(kk - tapBase) * 4096 + row * 64 + (((h * 4 + lg) ^ (row & 7)) << 3)]);
            }
        #pragma unroll
        for (int rg = 0; rg < 4; ++rg) {
            int nbr = nbrk[rg][kk];
            int pc  = nbr >= 0 ? nbr : 0;
            const uint4* ap = (const uint4*)(haB + (size_t)pc * 64) + lg;
            uint4 a0 = ap[0], a1 = ap[4];
            if (nbr < 0) { a0 = uint4{0,0,0,0}; a1 = uint4{0,0,0,0}; }
            s16x8 af0 = *reinterpret_cast<const s16x8*>(&a0);
            s16x8 af1 = *reinterpret_cast<const s16x8*>(&a1);
            #pragma unroll
            for (int nt = 0; nt < 4; ++nt)
                acc[rg][nt] = __builtin_amdgcn_mfma_f32_16x16x32_bf16(af0, bf[0][nt], acc[rg][nt], 0, 0, 0);
            #pragma unroll
            for (int nt = 0; nt < 4; ++nt)
                acc[rg][nt] = __builtin_amdgcn_mfma_f32_16x16x32_bf16(af1, bf[1][nt], acc[rg][nt], 0, 0, 0);
        }
    };

    stage(0, 5);
    __syncthreads();
    for (int kk = 0; kk < 5; ++kk) computeTap(kk, 0);
    __syncthreads();
    stage(5, 4);
    __syncthreads();
    for (int kk = 5; kk < 9; ++kk) computeTap(kk, 5);

    const float nsc = ns1[0];
    #pragma unroll
    for (int rg = 0; rg < 4; ++rg) {
        float p00[4] = {}, p01[4] = {}, p02[4] = {};
        float p10[4] = {}, p11[4] = {}, p12[4] = {};
        #pragma unroll
        for (int nt = 0; nt < 4; ++nt) {
            int o = nt * 16 + lr;
            float bias = b1[o];
            float st0  = stS[o], st1 = stS[64 + o];
            float wt0 = WtF[o], wt1 = WtF[64 + o], wt2 = WtF[128 + o];
            float w00 = wt0 * st0, w01 = wt1 * st0, w02 = wt2 * st0;
            float w10 = wt0 * st1, w11 = wt1 * st1, w12 = wt2 * st1;
            #pragma unroll
            for (int r = 0; r < 4; ++r) {
                int node = wbase + rg * 16 + lg * 4 + r;
                float v  = actf(acc[rg][nt][r] + nc1[node & (F_F - 1)] * nsc + bias);
                hOut[(size_t)node * 64 + o] = v;
                p00[r] += v * w00; p01[r] += v * w01; p02[r] += v * w02;
                p10[r] += v * w10; p11[r] += v * w11; p12[r] += v * w12;
            }
        }
        #pragma unroll
        for (int m = 1; m < 16; m <<= 1) {
            #pragma unroll
            for (int r = 0; r < 4; ++r) {
                p00[r] += __shfl_xor(p00[r], m, 64);
                p01[r] += __shfl_xor(p01[r], m, 64);
                p02[r] += __shfl_xor(p02[r], m, 64);
                p10[r] += __shfl_xor(p10[r], m, 64);
                p11[r] += __shfl_xor(p11[r], m, 64);
                p12[r] += __shfl_xor(p12[r], m, 64);
            }
        }
        if (lr == 0) {
            #pragma unroll
            for (int r = 0; r < 4; ++r) {
                int node = wbase + rg * 16 + lg * 4 + r;
                yPre2[(size_t)node * 6 + 0] = p00[r];
                yPre2[(size_t)node * 6 + 1] = p01[r];
                yPre2[(size_t)node * 6 + 2] = p02[r];
                yPre2[(size_t)node * 6 + 3] = p10[r];
                yPre2[(size_t)node * 6 + 4] = p11[r];
                yPre2[(size_t)node * 6 + 5] = p12[r];
            }
        }
    }
}

// ---------------- img upsample + yPre2 gather -> img (d_out tail) ----------------
__global__ __launch_bounds__(256)
void k_rgb(const float* __restrict__ yPre2,
           const float* __restrict__ imgF,
           const int*  __restrict__ fn1,
           const int*  __restrict__ fip1,
           const int*  __restrict__ pool,
           const float* __restrict__ btF,
           float* __restrict__ outImg)
{
    const int n = blockIdx.x * 256 + threadIdx.x;
    const int bOut = n / F_F;
    int fn[K2c], ip[K2c];
    #pragma unroll
    for (int k = 0; k < K2c; ++k) {
        fn[k] = fn1[(size_t)n * K2c + k];
        ip[k] = fip1[(size_t)n * K2c + k];
    }
    int pm[K2c], cnt = 0;
    #pragma unroll
    for (int k = 0; k < K2c; ++k) {
        int v  = !ip[k];
        cnt   += v;
        pm[k]  = (v && fn[k] < N1) ? pool[fn[k]] : -1;
    }
    float sr = 0.f, sg = 0.f, sb = 0.f;
    #pragma unroll
    for (int k = 0; k < K2c; ++k) {
        int   pc = pm[k] >= 0 ? pm[k] : 0;
        float m  = pm[k] >= 0 ? 1.f : 0.f;
        sr += m * imgF[(size_t)pc * 3 + 0];
        sg += m * imgF[(size_t)pc * 3 + 1];
        sb += m * imgF[(size_t)pc * 3 + 2];
    }
    int nb0 = (!ip[0] && fn[0] < N1) ? fn[0] : -1;
    float y0 = 0.f, y1 = 0.f, y2 = 0.f;
    if (nb0 >= 0) {
        const float* yp = yPre2 + (size_t)nb0 * 6 + bOut * 3;
        y0 = yp[0]; y1 = yp[1]; y2 = yp[2];
    }
    float ic = 1.f / (float)(cnt > 0 ? cnt : 1);
    y0 = fminf(fmaxf(y0 + btF[0], -256.f), 256.f);
    y1 = fminf(fmaxf(y1 + btF[1], -256.f), 256.f);
    y2 = fminf(fmaxf(y2 + btF[2], -256.f), 256.f);
    outImg[(size_t)n * 3 + 0] = sr * ic + y0;
    outImg[(size_t)n * 3 + 1] = sg * ic + y1;
    outImg[(size_t)n * 3 + 2] = sb * ic + y2;
}

// ---------------- host ----------------
extern "C" void kernel_launch(void* const* d_in, const int* in_sizes, int n_in,
                              void* d_out, int out_size, void* d_ws, size_t ws_size,
                              hipStream_t stream)
{
    const float* xF   = (const float*)d_in[0];
    const float* imgF = (const float*)d_in[1];
    const float* wsF  = (const float*)d_in[2];
    const float* a0w  = (const float*)d_in[3];
    const float* a0b  = (const float*)d_in[4];
    const float* W0w  = (const float*)d_in[5];
    const float* b0w  = (const float*)d_in[6];
    const float* ns0  = (const float*)d_in[7];
    const float* nc0  = (const float*)d_in[8];
    const float* a1w  = (const float*)d_in[9];
    const float* a1b  = (const float*)d_in[10];
    const float* W1w  = (const float*)d_in[11];
    const float* b1w  = (const float*)d_in[12];
    const float* ns1  = (const float*)d_in[13];
    const float* nc1  = (const float*)d_in[14];
    const float* atw  = (const float*)d_in[15];
    const float* atb  = (const float*)d_in[16];
    const float* WtF  = (const float*)d_in[17];
    const float* btF  = (const float*)d_in[18];
    const int* fn0  = (const int*)d_in[19];
    const int* fip0 = (const int*)d_in[20];
    const int* fn1  = (const int*)d_in[21];
    const int* fip1 = (const int*)d_in[22];
    const int* pool = (const int*)d_in[23];

    char* wsb = (char*)d_ws;
    float* fr = (float*)wsb;
    unsigned short* wm0T = (unsigned short*)(wsb + OFF_WM0T);
    unsigned short* wm1T = (unsigned short*)(wsb + OFF_WM1T);
    unsigned short* h0B  = (unsigned short*)(wsb + OFF_H0);
    unsigned short* haB  = (unsigned short*)(wsb + OFF_HA);
    unsigned short* xB   = (unsigned short*)(wsb + OFF_XB);   // overlays haB (dead until k_ha)
    float* yPre2         = (float*)(wsb + OFF_YPRE);          // overlays h0B (dead after k_ha)

    float* hOut   = (float*)d_out;
    float* imgOut = hOut + (size_t)N1 * 64;

    hipLaunchKernelGGL(k_styles, dim3(512), dim3(64), 0, stream,
                       wsF, a0w, a0b, a1w, a1b, atw, atb, fr);
    hipLaunchKernelGGL(k_wmod, dim3(256), dim3(256), 0, stream,
                       W0w, W1w, fr, wm0T, wm1T);
    hipLaunchKernelGGL(k_xcvt, dim3((N0 * C_IN) / 4 / 256), dim3(256), 0, stream,
                       xF, xB);
    hipLaunchKernelGGL(k_layer0, dim3(N0 / 256), dim3(256), 0, stream,
                       xB, fn0, fip0, wm0T, h0B);
    hipLaunchKernelGGL(k_ha, dim3(N1 / 32), dim3(256), 0, stream,
                       h0B, fn1, fip1, pool, nc0, ns0, b0w, haB);
    hipLaunchKernelGGL(k_layer1, dim3(N1 / 256), dim3(256), 0, stream,
                       haB, fn1, fip1, wm1T, nc1, ns1, b1w,
                       fr + FO_ST, WtF, hOut, yPre2);
    hipLaunchKernelGGL(k_rgb, dim3(N1 / 256), dim3(256), 0, stream,
                       yPre2, imgF, fn1, fip1, pool, btF, imgOut);
}

// Round 13
// 191.856 us; speedup vs baseline: 1.6477x; 1.6477x over previous
//
#include <hip/hip_runtime.h>
#include <hip/hip_bf16.h>

// ---------------- problem constants ----------------
constexpr int F_C   = 32768;
constexpr int F_F   = 131072;
constexpr int N0    = 65536;    // B*F_C
constexpr int N1    = 262144;   // B*F_F
constexpr int C_IN  = 128;
constexpr int W_DIM = 512;
constexpr int K2c   = 9;
constexpr float RS512     = 0.04419417382415922f;   // 1/sqrt(512)
constexpr float ACT_GAINc = 1.4142135623730951f;    // sqrt(2)

// ---------------- workspace layout ----------------
constexpr size_t FO_S0  = 0;
constexpr size_t FO_S1  = 256;
constexpr size_t FO_ST  = 384;
constexpr size_t OFF_WM0T = 2048;                    // [2][9][64 o][128 ci] u16 = 294912 B
constexpr size_t OFF_WM1T = OFF_WM0T + 294912;       // [2][9][64 o][64 ci] u16 = 147456 B
constexpr size_t OFF_H0   = 458752;                  // bf16 h0: 65536*64*2  = 8388608
constexpr size_t OFF_HA   = OFF_H0 + (size_t)8388608;// bf16 ha: 262144*64*2 = 33554432
// yPre2 (N1*6 f32) reuses the h0 region (h0B dead after k_ha).
constexpr size_t OFF_YPRE = OFF_H0;
// xB (bf16 copy of x) overlays the haB region (dead until k_ha runs).
constexpr size_t OFF_XB   = OFF_HA;

typedef short s16x8 __attribute__((ext_vector_type(8)));
typedef float f32x4 __attribute__((ext_vector_type(4)));

// ---------------- helpers ----------------
__device__ __forceinline__ float b2f(unsigned short u) {
    union { unsigned int i; float f; } v; v.i = ((unsigned int)u) << 16; return v.f;
}
__device__ __forceinline__ unsigned short f2b(float f) {
    __hip_bfloat16 h = __float2bfloat16(f);
    return *reinterpret_cast<unsigned short*>(&h);
}
__device__ __forceinline__ float waveRedSum(float v) {
    for (int m = 32; m; m >>= 1) v += __shfl_xor(v, m, 64);
    return v;
}
__device__ __forceinline__ float actf(float v) {
    float y = (v >= 0.f) ? v : 0.2f * v;
    y *= ACT_GAINc;
    return fminf(fmaxf(y, -256.f), 256.f);
}

// ---------------- styles ----------------
__global__ __launch_bounds__(64)
void k_styles(const float* __restrict__ wsF,
              const float* __restrict__ a0w, const float* __restrict__ a0b,
              const float* __restrict__ a1w, const float* __restrict__ a1b,
              const float* __restrict__ atw, const float* __restrict__ atb,
              float* __restrict__ fr)
{
    int bid = blockIdx.x, lane = threadIdx.x;
    int bb, ii, ll, row; const float *aw, *ab; float* dst; float post = 1.f;
    if (bid < 256)      { bb = bid >> 7;             ii = bid & 127; ll = 0; aw = a0w; ab = a0b; dst = fr + FO_S0; row = 128; }
    else if (bid < 384) { int t = bid - 256; bb = t >> 6; ii = t & 63; ll = 1; aw = a1w; ab = a1b; dst = fr + FO_S1; row = 64; }
    else                { int t = bid - 384; bb = t >> 6; ii = t & 63; ll = 2; aw = atw; ab = atb; dst = fr + FO_ST; row = 64; post = 0.125f; }
    const float* wsv = wsF + (size_t)(bb * 3 + ll) * W_DIM;
    const float* awr = aw + (size_t)ii * W_DIM;
    float s = 0.f;
    for (int j = lane; j < W_DIM; j += 64) s += wsv[j] * awr[j];
    s = waveRedSum(s);
    if (lane == 0) dst[bb * row + ii] = (s * RS512 + ab[ii]) * post;
}

// ---------------- demodulated weights -> wmodT[b][k][o][ci] (bf16) ----------------
__global__ __launch_bounds__(256)
void k_wmod(const float* __restrict__ W0,
            const float* __restrict__ W1,
            const float* __restrict__ fr,
            unsigned short* __restrict__ wm0T,
            unsigned short* __restrict__ wm1T)
{
    int bo = blockIdx.x, tid = threadIdx.x;
    int b, o, CI, NE; const float* W; const float* S; unsigned short* dst;
    if (bo < 128) { b = bo >> 6; o = bo & 63; CI = 128; NE = 1152; W = W0; S = fr + FO_S0; dst = wm0T; }
    else { int t = bo - 128; b = t >> 6; o = t & 63; CI = 64; NE = 576; W = W1; S = fr + FO_S1; dst = wm1T; }
    const float* Wo = W + (size_t)o * NE;
    const float* Sb = S + (size_t)b * CI;
    float ss = 0.f;
    for (int idx = tid; idx < NE; idx += 256) {
        int i = idx / K2c;
        float p = Wo[idx] * Sb[i];
        ss += p * p;
    }
    __shared__ float red[4];
    float s = waveRedSum(ss);
    if ((tid & 63) == 0) red[tid >> 6] = s;
    __syncthreads();
    float d = rsqrtf(red[0] + red[1] + red[2] + red[3] + 1e-8f);
    for (int idx = tid; idx < NE; idx += 256) {
        int i = idx / K2c, kk = idx - i * K2c;
        dst[((size_t)(b * K2c + kk) * 64 + o) * CI + i] = f2b(Wo[idx] * Sb[i] * d);
    }
}

// ---------------- x f32 -> bf16 copy (coalesced) ----------------
__global__ __launch_bounds__(256)
void k_xcvt(const float* __restrict__ xF, unsigned short* __restrict__ xB)
{
    int i = blockIdx.x * 256 + threadIdx.x;
    float4 f = ((const float4*)xF)[i];
    union { unsigned short u[4]; uint2 v; } t;
    t.u[0] = f2b(f.x); t.u[1] = f2b(f.y); t.u[2] = f2b(f.z); t.u[3] = f2b(f.w);
    ((uint2*)xB)[i] = t.v;
}

// ---------------- layer0: all-taps W LDS per K-half (72 KB, 2 blk/CU), A direct ----------------
__global__ __launch_bounds__(256, 2)
void k_layer0(const unsigned short* __restrict__ xB,
              const int*  __restrict__ fn0,
              const int*  __restrict__ fip0,
              const unsigned short* __restrict__ wm0T,   // [b][k][o][128] bf16
              unsigned short* __restrict__ h0B)
{
    __shared__ unsigned short W_lds[9 * 4096];   // 72 KB, one K-half of all 9 taps
    const int tid  = threadIdx.x;
    const int g0   = blockIdx.x * 256;
    const int b    = g0 / F_C;
    const int wave = tid >> 6, lane = tid & 63;
    const int lg   = lane >> 4, lr = lane & 15;
    const int wbase = g0 + wave * 64;
    const unsigned short* wtap = wm0T + (size_t)b * K2c * 64 * C_IN;

    int nbrk[4][9];
    #pragma unroll
    for (int rg = 0; rg < 4; ++rg) {
        int row = wbase + rg * 16 + lr;
        #pragma unroll
        for (int k = 0; k < 9; ++k) {
            int fn = fn0[(size_t)row * 9 + k];
            int ip = fip0[(size_t)row * 9 + k];
            nbrk[rg][k] = (!ip && fn < N0) ? fn : -1;
        }
    }

    f32x4 acc[4][4] = {};
    for (int h = 0; h < 2; ++h) {
        __syncthreads();     // h=1: ensure previous compute done before overwrite
        #pragma unroll
        for (int t = 0; t < 18; ++t) {               // 4608 chunks
            int idx = tid + 256 * t;
            int tap = idx >> 9;
            int rem = idx & 511;
            int row = rem >> 3, cc = rem & 7;        // 8 chunks per 64-ci row
            uint4 v = *(const uint4*)(wtap + ((size_t)tap * 64 + row) * C_IN + h * 64 + cc * 8);
            *(uint4*)(&W_lds[tap * 4096 + row * 64 + ((cc ^ (row & 7)) << 3)]) = v;
        }
        __syncthreads();
        #pragma unroll
        for (int kk = 0; kk < 9; ++kk) {
            s16x8 bf[2][4];
            #pragma unroll
            for (int c2 = 0; c2 < 2; ++c2)
                #pragma unroll
                for (int nt = 0; nt < 4; ++nt) {
                    int row = nt * 16 + lr;
                    bf[c2][nt] = *(const s16x8*)(&W_lds[kk * 4096 + row * 64 + (((c2 * 4 + lg) ^ (row & 7)) << 3)]);
                }
            #pragma unroll
            for (int rg = 0; rg < 4; ++rg) {
                int nbr = nbrk[rg][kk];
                int pc  = nbr >= 0 ? nbr : 0;
                const uint4* ap = (const uint4*)(xB + (size_t)pc * C_IN) + lg;
                uint4 a0 = ap[h * 8];                // k-chunk 0 of this half
                uint4 a1 = ap[h * 8 + 4];            // k-chunk 1
                if (nbr < 0) { a0 = uint4{0,0,0,0}; a1 = uint4{0,0,0,0}; }
                s16x8 af0 = *reinterpret_cast<const s16x8*>(&a0);
                s16x8 af1 = *reinterpret_cast<const s16x8*>(&a1);
                #pragma unroll
                for (int nt = 0; nt < 4; ++nt)
                    acc[rg][nt] = __builtin_amdgcn_mfma_f32_16x16x32_bf16(af0, bf[0][nt], acc[rg][nt], 0, 0, 0);
                #pragma unroll
                for (int nt = 0; nt < 4; ++nt)
                    acc[rg][nt] = __builtin_amdgcn_mfma_f32_16x16x32_bf16(af1, bf[1][nt], acc[rg][nt], 0, 0, 0);
            }
        }
    }
    #pragma unroll
    for (int rg = 0; rg < 4; ++rg)
        #pragma unroll
        for (int nt = 0; nt < 4; ++nt) {
            int o = nt * 16 + lr;
            #pragma unroll
            for (int r = 0; r < 4; ++r) {
                int node = wbase + rg * 16 + lg * 4 + r;
                h0B[(size_t)node * 64 + o] = f2b(acc[rg][nt][r]);
            }
        }
}

// ---------------- smooth upsample + noise + bias + act -> ha ----------------
__global__ __launch_bounds__(256)
void k_ha(const unsigned short* __restrict__ h0B,
          const int*  __restrict__ fn1,
          const int*  __restrict__ fip1,
          const int*  __restrict__ pool,
          const float* __restrict__ nc0,
          const float* __restrict__ ns0,
          const float* __restrict__ b0,
          unsigned short* __restrict__ haB)
{
    __shared__ int   pmArr[288];
    __shared__ int   vArr[288];
    __shared__ float invCnt[32];
    const int tid = threadIdx.x;
    const int n0  = blockIdx.x * 32;
    for (int idx = tid; idx < 288; idx += 256) {
        int fn = fn1[(size_t)n0 * K2c + idx];
        int ip = fip1[(size_t)n0 * K2c + idx];
        int v  = !ip;
        int pm = -1;
        if (v && fn < N1) pm = pool[fn];
        pmArr[idx] = pm;
        vArr[idx]  = v;
    }
    __syncthreads();
    if (tid < 32) {
        int c = 0;
        #pragma unroll
        for (int k = 0; k < K2c; ++k) c += vArr[tid * K2c + k];
        invCnt[tid] = 1.f / (float)(c > 0 ? c : 1);
    }
    __syncthreads();
    const int wave = tid >> 6, lane = tid & 63;
    const float nsc  = ns0[0];
    const float bias = b0[lane];
    for (int jj = 0; jj < 8; ++jj) {
        int node = wave * 8 + jj;
        int g    = n0 + node;
        float acc = 0.f;
        #pragma unroll
        for (int k = 0; k < K2c; ++k) {
            int pm = pmArr[node * K2c + k];
            int pc = pm >= 0 ? pm : 0;
            float val = b2f(h0B[(size_t)pc * 64 + lane]);
            acc += (pm >= 0) ? val : 0.f;
        }
        float hu = acc * invCnt[node];
        float v  = hu + nc0[g & (F_F - 1)] * nsc + bias;
        haB[(size_t)g * 64 + lane] = f2b(actf(v));
    }
}

// ---------------- layer1: round-10 structure + depth-2 A-gather register prefetch ----------------
__global__ __launch_bounds__(256, 2)
void k_layer1(const unsigned short* __restrict__ haB,
              const int*  __restrict__ fn1,
              const int*  __restrict__ fip1,
              const unsigned short* __restrict__ wm1T,   // [b][k][o][64] bf16
              const float* __restrict__ nc1,
              const float* __restrict__ ns1,
              const float* __restrict__ b1,
              const float* __restrict__ stS,     // [2][64], already * 1/sqrt(64)
              const float* __restrict__ WtF,     // [3][64]
              float* __restrict__ hOut,
              float* __restrict__ yPre2)         // [N1][2][3]
{
    __shared__ unsigned short W_lds[9 * 4096];   // 73728 B, swizzled chunks
    const int tid  = threadIdx.x;
    const int g0   = blockIdx.x * 256;
    const int b    = g0 / F_F;
    const int wave = tid >> 6, lane = tid & 63;
    const int lg   = lane >> 4, lr = lane & 15;
    const int wbase = g0 + wave * 64;
    const unsigned short* wtap = wm1T + (size_t)b * K2c * 4096;

    // stage all 9 taps; logical 16B-chunk c of row stored at chunk (c ^ (row&7))
    #pragma unroll
    for (int t = 0; t < 18; ++t) {
        int idx = tid + 256 * t;
        int tap = idx >> 9;
        int rem = idx & 511;
        int row = rem >> 3, c = rem & 7;
        uint4 v = ((const uint4*)wtap)[idx];
        *(uint4*)(&W_lds[tap * 4096 + row * 64 + ((c ^ (row & 7)) << 3)]) = v;
    }

    int nbrk[4][9];
    #pragma unroll
    for (int rg = 0; rg < 4; ++rg) {
        int row = wbase + rg * 16 + lr;
        #pragma unroll
        for (int k = 0; k < 9; ++k) {
            int fn = fn1[(size_t)row * 9 + k];
            int ip = fip1[(size_t)row * 9 + k];
            nbrk[rg][k] = (!ip && fn < N1) ? fn : -1;
        }
    }

    // depth-2 prefetch: issue taps 0 and 1 (independent of LDS staging)
    uint4 pa[2][4][2];
    #pragma unroll
    for (int kk = 0; kk < 2; ++kk)
        #pragma unroll
        for (int rg = 0; rg < 4; ++rg) {
            int nbr = nbrk[rg][kk];
            int pc  = nbr >= 0 ? nbr : 0;
            const uint4* ap = (const uint4*)(haB + (size_t)pc * 64) + lg;
            pa[kk][rg][0] = ap[0];
            pa[kk][rg][1] = ap[4];
        }

    __syncthreads();     // the ONLY barrier

    f32x4 acc[4][4] = {};   // [rg][nt]
    #pragma unroll
    for (int kk = 0; kk < 9; ++kk) {
        const int slot = kk & 1;
        s16x8 bf[2][4];
        #pragma unroll
        for (int h = 0; h < 2; ++h)
            #pragma unroll
            for (int nt = 0; nt < 4; ++nt) {
                int row = nt * 16 + lr;
                bf[h][nt] = *(const s16x8*)(&W_lds[kk * 4096 + row * 64 + (((h * 4 + lg) ^ (row & 7)) << 3)]);
            }
        // pull current tap's fragments out of the prefetch slot
        uint4 cur[4][2];
        #pragma unroll
        for (int rg = 0; rg < 4; ++rg) {
            cur[rg][0] = pa[slot][rg][0];
            cur[rg][1] = pa[slot][rg][1];
        }
        // refill the slot with tap kk+2 (latency hides under this tap's MFMAs)
        if (kk + 2 < 9) {
            #pragma unroll
            for (int rg = 0; rg < 4; ++rg) {
                int nbr = nbrk[rg][kk + 2];
                int pc  = nbr >= 0 ? nbr : 0;
                const uint4* ap = (const uint4*)(haB + (size_t)pc * 64) + lg;
                pa[slot][rg][0] = ap[0];
                pa[slot][rg][1] = ap[4];
            }
        }
        #pragma unroll
        for (int rg = 0; rg < 4; ++rg) {
            int nbr = nbrk[rg][kk];
            uint4 a0 = cur[rg][0], a1 = cur[rg][1];
            if (nbr < 0) { a0 = uint4{0,0,0,0}; a1 = uint4{0,0,0,0}; }
            s16x8 af0 = *reinterpret_cast<const s16x8*>(&a0);
            s16x8 af1 = *reinterpret_cast<const s16x8*>(&a1);
            #pragma unroll
            for (int nt = 0; nt < 4; ++nt)
                acc[rg][nt] = __builtin_amdgcn_mfma_f32_16x16x32_bf16(af0, bf[0][nt], acc[rg][nt], 0, 0, 0);
            #pragma unroll
            for (int nt = 0; nt < 4; ++nt)
                acc[rg][nt] = __builtin_amdgcn_mfma_f32_16x16x32_bf16(af1, bf[1][nt], acc[rg][nt], 0, 0, 0);
        }
    }

    const float nsc = ns1[0];
    #pragma unroll
    for (int rg = 0; rg < 4; ++rg) {
        float p00[4] = {}, p01[4] = {}, p02[4] = {};
        float p10[4] = {}, p11[4] = {}, p12[4] = {};
        #pragma unroll
        for (int nt = 0; nt < 4; ++nt) {
            int o = nt * 16 + lr;
            float bias = b1[o];
            float st0  = stS[o], st1 = stS[64 + o];
            float wt0 = WtF[o], wt1 = WtF[64 + o], wt2 = WtF[128 + o];
            float w00 = wt0 * st0, w01 = wt1 * st0, w02 = wt2 * st0;
            float w10 = wt0 * st1, w11 = wt1 * st1, w12 = wt2 * st1;
            #pragma unroll
            for (int r = 0; r < 4; ++r) {
                int node = wbase + rg * 16 + lg * 4 + r;
                float v  = actf(acc[rg][nt][r] + nc1[node & (F_F - 1)] * nsc + bias);
                hOut[(size_t)node * 64 + o] = v;
                p00[r] += v * w00; p01[r] += v * w01; p02[r] += v * w02;
                p10[r] += v * w10; p11[r] += v * w11; p12[r] += v * w12;
            }
        }
        #pragma unroll
        for (int m = 1; m < 16; m <<= 1) {
            #pragma unroll
            for (int r = 0; r < 4; ++r) {
                p00[r] += __shfl_xor(p00[r], m, 64);
                p01[r] += __shfl_xor(p01[r], m, 64);
                p02[r] += __shfl_xor(p02[r], m, 64);
                p10[r] += __shfl_xor(p10[r], m, 64);
                p11[r] += __shfl_xor(p11[r], m, 64);
                p12[r] += __shfl_xor(p12[r], m, 64);
            }
        }
        if (lr == 0) {
            #pragma unroll
            for (int r = 0; r < 4; ++r) {
                int node = wbase + rg * 16 + lg * 4 + r;
                yPre2[(size_t)node * 6 + 0] = p00[r];
                yPre2[(size_t)node * 6 + 1] = p01[r];
                yPre2[(size_t)node * 6 + 2] = p02[r];
                yPre2[(size_t)node * 6 + 3] = p10[r];
                yPre2[(size_t)node * 6 + 4] = p11[r];
                yPre2[(size_t)node * 6 + 5] = p12[r];
            }
        }
    }
}

// ---------------- img upsample + yPre2 gather -> img (d_out tail) ----------------
__global__ __launch_bounds__(256)
void k_rgb(const float* __restrict__ yPre2,
           const float* __restrict__ imgF,
           const int*  __restrict__ fn1,
           const int*  __restrict__ fip1,
           const int*  __restrict__ pool,
           const float* __restrict__ btF,
           float* __restrict__ outImg)
{
    const int n = blockIdx.x * 256 + threadIdx.x;
    const int bOut = n / F_F;
    int fn[K2c], ip[K2c];
    #pragma unroll
    for (int k = 0; k < K2c; ++k) {
        fn[k] = fn1[(size_t)n * K2c + k];
        ip[k] = fip1[(size_t)n * K2c + k];
    }
    int pm[K2c], cnt = 0;
    #pragma unroll
    for (int k = 0; k < K2c; ++k) {
        int v  = !ip[k];
        cnt   += v;
        pm[k]  = (v && fn[k] < N1) ? pool[fn[k]] : -1;
    }
    float sr = 0.f, sg = 0.f, sb = 0.f;
    #pragma unroll
    for (int k = 0; k < K2c; ++k) {
        int   pc = pm[k] >= 0 ? pm[k] : 0;
        float m  = pm[k] >= 0 ? 1.f : 0.f;
        sr += m * imgF[(size_t)pc * 3 + 0];
        sg += m * imgF[(size_t)pc * 3 + 1];
        sb += m * imgF[(size_t)pc * 3 + 2];
    }
    int nb0 = (!ip[0] && fn[0] < N1) ? fn[0] : -1;
    float y0 = 0.f, y1 = 0.f, y2 = 0.f;
    if (nb0 >= 0) {
        const float* yp = yPre2 + (size_t)nb0 * 6 + bOut * 3;
        y0 = yp[0]; y1 = yp[1]; y2 = yp[2];
    }
    float ic = 1.f / (float)(cnt > 0 ? cnt : 1);
    y0 = fminf(fmaxf(y0 + btF[0], -256.f), 256.f);
    y1 = fminf(fmaxf(y1 + btF[1], -256.f), 256.f);
    y2 = fminf(fmaxf(y2 + btF[2], -256.f), 256.f);
    outImg[(size_t)n * 3 + 0] = sr * ic + y0;
    outImg[(size_t)n * 3 + 1] = sg * ic + y1;
    outImg[(size_t)n * 3 + 2] = sb * ic + y2;
}

// ---------------- host ----------------
extern "C" void kernel_launch(void* const* d_in, const int* in_sizes, int n_in,
                              void* d_out, int out_size, void* d_ws, size_t ws_size,
                              hipStream_t stream)
{
    const float* xF   = (const float*)d_in[0];
    const float* imgF = (const float*)d_in[1];
    const float* wsF  = (const float*)d_in[2];
    const float* a0w  = (const float*)d_in[3];
    const float* a0b  = (const float*)d_in[4];
    const float* W0w  = (const float*)d_in[5];
    const float* b0w  = (const float*)d_in[6];
    const float* ns0  = (const float*)d_in[7];
    const float* nc0  = (const float*)d_in[8];
    const float* a1w  = (const float*)d_in[9];
    const float* a1b  = (const float*)d_in[10];
    const float* W1w  = (const float*)d_in[11];
    const float* b1w  = (const float*)d_in[12];
    const float* ns1  = (const float*)d_in[13];
    const float* nc1  = (const float*)d_in[14];
    const float* atw  = (const float*)d_in[15];
    const float* atb  = (const float*)d_in[16];
    const float* WtF  = (const float*)d_in[17];
    const float* btF  = (const float*)d_in[18];
    const int* fn0  = (const int*)d_in[19];
    const int* fip0 = (const int*)d_in[20];
    const int* fn1  = (const int*)d_in[21];
    const int* fip1 = (const int*)d_in[22];
    const int* pool = (const int*)d_in[23];

    char* wsb = (char*)d_ws;
    float* fr = (float*)wsb;
    unsigned short* wm0T = (unsigned short*)(wsb + OFF_WM0T);
    unsigned short* wm1T = (unsigned short*)(wsb + OFF_WM1T);
    unsigned short* h0B  = (unsigned short*)(wsb + OFF_H0);
    unsigned short* haB  = (unsigned short*)(wsb + OFF_HA);
    unsigned short* xB   = (unsigned short*)(wsb + OFF_XB);   // overlays haB (dead until k_ha)
    float* yPre2         = (float*)(wsb + OFF_YPRE);          // overlays h0B (dead after k_ha)

    float* hOut   = (float*)d_out;
    float* imgOut = hOut + (size_t)N1 * 64;

    hipLaunchKernelGGL(k_styles, dim3(512), dim3(64), 0, stream,
                       wsF, a0w, a0b, a1w, a1b, atw, atb, fr);
    hipLaunchKernelGGL(k_wmod, dim3(256), dim3(256), 0, stream,
                       W0w, W1w, fr, wm0T, wm1T);
    hipLaunchKernelGGL(k_xcvt, dim3((N0 * C_IN) / 4 / 256), dim3(256), 0, stream,
                       xF, xB);
    hipLaunchKernelGGL(k_layer0, dim3(N0 / 256), dim3(256), 0, stream,
                       xB, fn0, fip0, wm0T, h0B);
    hipLaunchKernelGGL(k_ha, dim3(N1 / 32), dim3(256), 0, stream,
                       h0B, fn1, fip1, pool, nc0, ns0, b0w, haB);
    hipLaunchKernelGGL(k_layer1, dim3(N1 / 256), dim3(256), 0, stream,
                       haB, fn1, fip1, wm1T, nc1, ns1, b1w,
                       fr + FO_ST, WtF, hOut, yPre2);
    hipLaunchKernelGGL(k_rgb, dim3(N1 / 256), dim3(256), 0, stream,
                       yPre2, imgF, fn1, fip1, pool, btF, imgOut);
}

// Round 14
// 189.939 us; speedup vs baseline: 1.6643x; 1.0101x over previous
//
#include <hip/hip_runtime.h>
#include <hip/hip_bf16.h>

// ---------------- problem constants ----------------
constexpr int F_C   = 32768;
constexpr int F_F   = 131072;
constexpr int N0    = 65536;    // B*F_C
constexpr int N1    = 262144;   // B*F_F
constexpr int C_IN  = 128;
constexpr int W_DIM = 512;
constexpr int K2c   = 9;
constexpr float RS512     = 0.04419417382415922f;   // 1/sqrt(512)
constexpr float ACT_GAINc = 1.4142135623730951f;    // sqrt(2)

// ---------------- workspace layout ----------------
constexpr size_t FO_S0  = 0;
constexpr size_t FO_S1  = 256;
constexpr size_t FO_ST  = 384;
constexpr size_t OFF_WM0T = 2048;                    // [2][9][64 o][128 ci] u16 = 294912 B
constexpr size_t OFF_WM1T = OFF_WM0T + 294912;       // [2][9][64 o][64 ci] u16 = 147456 B
constexpr size_t OFF_H0   = 458752;                  // bf16 h0: 65536*64*2  = 8388608
constexpr size_t OFF_HA   = OFF_H0 + (size_t)8388608;// bf16 ha: 262144*64*2 = 33554432
// yPre2 (N1*6 f32) reuses the h0 region (h0B dead after k_ha).
constexpr size_t OFF_YPRE = OFF_H0;
// xB (bf16 copy of x) overlays the haB region (dead until k_ha runs).
constexpr size_t OFF_XB   = OFF_HA;

typedef short s16x8 __attribute__((ext_vector_type(8)));
typedef float f32x4 __attribute__((ext_vector_type(4)));

// ---------------- helpers ----------------
__device__ __forceinline__ float b2f(unsigned short u) {
    union { unsigned int i; float f; } v; v.i = ((unsigned int)u) << 16; return v.f;
}
__device__ __forceinline__ unsigned short f2b(float f) {
    __hip_bfloat16 h = __float2bfloat16(f);
    return *reinterpret_cast<unsigned short*>(&h);
}
__device__ __forceinline__ float waveRedSum(float v) {
    for (int m = 32; m; m >>= 1) v += __shfl_xor(v, m, 64);
    return v;
}
__device__ __forceinline__ float actf(float v) {
    float y = (v >= 0.f) ? v : 0.2f * v;
    y *= ACT_GAINc;
    return fminf(fmaxf(y, -256.f), 256.f);
}

// ---------------- styles ----------------
__global__ __launch_bounds__(64)
void k_styles(const float* __restrict__ wsF,
              const float* __restrict__ a0w, const float* __restrict__ a0b,
              const float* __restrict__ a1w, const float* __restrict__ a1b,
              const float* __restrict__ atw, const float* __restrict__ atb,
              float* __restrict__ fr)
{
    int bid = blockIdx.x, lane = threadIdx.x;
    int bb, ii, ll, row; const float *aw, *ab; float* dst; float post = 1.f;
    if (bid < 256)      { bb = bid >> 7;             ii = bid & 127; ll = 0; aw = a0w; ab = a0b; dst = fr + FO_S0; row = 128; }
    else if (bid < 384) { int t = bid - 256; bb = t >> 6; ii = t & 63; ll = 1; aw = a1w; ab = a1b; dst = fr + FO_S1; row = 64; }
    else                { int t = bid - 384; bb = t >> 6; ii = t & 63; ll = 2; aw = atw; ab = atb; dst = fr + FO_ST; row = 64; post = 0.125f; }
    const float* wsv = wsF + (size_t)(bb * 3 + ll) * W_DIM;
    const float* awr = aw + (size_t)ii * W_DIM;
    float s = 0.f;
    for (int j = lane; j < W_DIM; j += 64) s += wsv[j] * awr[j];
    s = waveRedSum(s);
    if (lane == 0) dst[bb * row + ii] = (s * RS512 + ab[ii]) * post;
}

// ---------------- demodulated weights -> wmodT[b][k][o][ci] (bf16) ----------------
__global__ __launch_bounds__(256)
void k_wmod(const float* __restrict__ W0,
            const float* __restrict__ W1,
            const float* __restrict__ fr,
            unsigned short* __restrict__ wm0T,
            unsigned short* __restrict__ wm1T)
{
    int bo = blockIdx.x, tid = threadIdx.x;
    int b, o, CI, NE; const float* W; const float* S; unsigned short* dst;
    if (bo < 128) { b = bo >> 6; o = bo & 63; CI = 128; NE = 1152; W = W0; S = fr + FO_S0; dst = wm0T; }
    else { int t = bo - 128; b = t >> 6; o = t & 63; CI = 64; NE = 576; W = W1; S = fr + FO_S1; dst = wm1T; }
    const float* Wo = W + (size_t)o * NE;
    const float* Sb = S + (size_t)b * CI;
    float ss = 0.f;
    for (int idx = tid; idx < NE; idx += 256) {
        int i = idx / K2c;
        float p = Wo[idx] * Sb[i];
        ss += p * p;
    }
    __shared__ float red[4];
    float s = waveRedSum(ss);
    if ((tid & 63) == 0) red[tid >> 6] = s;
    __syncthreads();
    float d = rsqrtf(red[0] + red[1] + red[2] + red[3] + 1e-8f);
    for (int idx = tid; idx < NE; idx += 256) {
        int i = idx / K2c, kk = idx - i * K2c;
        dst[((size_t)(b * K2c + kk) * 64 + o) * CI + i] = f2b(Wo[idx] * Sb[i] * d);
    }
}

// ---------------- x f32 -> bf16 copy (coalesced) ----------------
__global__ __launch_bounds__(256)
void k_xcvt(const float* __restrict__ xF, unsigned short* __restrict__ xB)
{
    int i = blockIdx.x * 256 + threadIdx.x;
    float4 f = ((const float4*)xF)[i];
    union { unsigned short u[4]; uint2 v; } t;
    t.u[0] = f2b(f.x); t.u[1] = f2b(f.y); t.u[2] = f2b(f.z); t.u[3] = f2b(f.w);
    ((uint2*)xB)[i] = t.v;
}

// ---------------- layer0: all-taps W LDS per K-half (72 KB, 2 blk/CU), A direct ----------------
__global__ __launch_bounds__(256, 2)
void k_layer0(const unsigned short* __restrict__ xB,
              const int*  __restrict__ fn0,
              const int*  __restrict__ fip0,
              const unsigned short* __restrict__ wm0T,   // [b][k][o][128] bf16
              unsigned short* __restrict__ h0B)
{
    __shared__ unsigned short W_lds[9 * 4096];   // 72 KB, one K-half of all 9 taps
    const int tid  = threadIdx.x;
    const int g0   = blockIdx.x * 256;
    const int b    = g0 / F_C;
    const int wave = tid >> 6, lane = tid & 63;
    const int lg   = lane >> 4, lr = lane & 15;
    const int wbase = g0 + wave * 64;
    const unsigned short* wtap = wm0T + (size_t)b * K2c * 64 * C_IN;

    int nbrk[4][9];
    #pragma unroll
    for (int rg = 0; rg < 4; ++rg) {
        int row = wbase + rg * 16 + lr;
        #pragma unroll
        for (int k = 0; k < 9; ++k) {
            int fn = fn0[(size_t)row * 9 + k];
            int ip = fip0[(size_t)row * 9 + k];
            nbrk[rg][k] = (!ip && fn < N0) ? fn : -1;
        }
    }

    f32x4 acc[4][4] = {};
    for (int h = 0; h < 2; ++h) {
        __syncthreads();     // h=1: ensure previous compute done before overwrite
        #pragma unroll
        for (int t = 0; t < 18; ++t) {               // 4608 chunks
            int idx = tid + 256 * t;
            int tap = idx >> 9;
            int rem = idx & 511;
            int row = rem >> 3, cc = rem & 7;        // 8 chunks per 64-ci row
            uint4 v = *(const uint4*)(wtap + ((size_t)tap * 64 + row) * C_IN + h * 64 + cc * 8);
            *(uint4*)(&W_lds[tap * 4096 + row * 64 + ((cc ^ (row & 7)) << 3)]) = v;
        }
        __syncthreads();
        #pragma unroll
        for (int kk = 0; kk < 9; ++kk) {
            s16x8 bf[2][4];
            #pragma unroll
            for (int c2 = 0; c2 < 2; ++c2)
                #pragma unroll
                for (int nt = 0; nt < 4; ++nt) {
                    int row = nt * 16 + lr;
                    bf[c2][nt] = *(const s16x8*)(&W_lds[kk * 4096 + row * 64 + (((c2 * 4 + lg) ^ (row & 7)) << 3)]);
                }
            #pragma unroll
            for (int rg = 0; rg < 4; ++rg) {
                int nbr = nbrk[rg][kk];
                int pc  = nbr >= 0 ? nbr : 0;
                const uint4* ap = (const uint4*)(xB + (size_t)pc * C_IN) + lg;
                uint4 a0 = ap[h * 8];                // k-chunk 0 of this half
                uint4 a1 = ap[h * 8 + 4];            // k-chunk 1
                if (nbr < 0) { a0 = uint4{0,0,0,0}; a1 = uint4{0,0,0,0}; }
                s16x8 af0 = *reinterpret_cast<const s16x8*>(&a0);
                s16x8 af1 = *reinterpret_cast<const s16x8*>(&a1);
                #pragma unroll
                for (int nt = 0; nt < 4; ++nt)
                    acc[rg][nt] = __builtin_amdgcn_mfma_f32_16x16x32_bf16(af0, bf[0][nt], acc[rg][nt], 0, 0, 0);
                #pragma unroll
                for (int nt = 0; nt < 4; ++nt)
                    acc[rg][nt] = __builtin_amdgcn_mfma_f32_16x16x32_bf16(af1, bf[1][nt], acc[rg][nt], 0, 0, 0);
            }
        }
    }
    #pragma unroll
    for (int rg = 0; rg < 4; ++rg)
        #pragma unroll
        for (int nt = 0; nt < 4; ++nt) {
            int o = nt * 16 + lr;
            #pragma unroll
            for (int r = 0; r < 4; ++r) {
                int node = wbase + rg * 16 + lg * 4 + r;
                h0B[(size_t)node * 64 + o] = f2b(acc[rg][nt][r]);
            }
        }
}

// ---------------- smooth upsample + noise + bias + act -> ha ----------------
// thread = (node, 8-channel group): per tap ONE uint4 load (16 B/lane),
// wave covers 8 rows x 128 B per instruction; 9 independent loads/thread.
__global__ __launch_bounds__(256)
void k_ha(const unsigned short* __restrict__ h0B,
          const int*  __restrict__ fn1,
          const int*  __restrict__ fip1,
          const int*  __restrict__ pool,
          const float* __restrict__ nc0,
          const float* __restrict__ ns0,
          const float* __restrict__ b0,
          unsigned short* __restrict__ haB)
{
    __shared__ int   pmArr[288];
    __shared__ int   vArr[288];
    __shared__ float invCnt[32];
    const int tid = threadIdx.x;
    const int n0  = blockIdx.x * 32;
    for (int idx = tid; idx < 288; idx += 256) {
        int fn = fn1[(size_t)n0 * K2c + idx];
        int ip = fip1[(size_t)n0 * K2c + idx];
        int v  = !ip;
        int pm = -1;
        if (v && fn < N1) pm = pool[fn];
        pmArr[idx] = pm;
        vArr[idx]  = v;
    }
    __syncthreads();
    if (tid < 32) {
        int c = 0;
        #pragma unroll
        for (int k = 0; k < K2c; ++k) c += vArr[tid * K2c + k];
        invCnt[tid] = 1.f / (float)(c > 0 ? c : 1);
    }
    __syncthreads();
    const int node = tid >> 3;      // 0..31
    const int cg   = tid & 7;       // 0..7  (8 channels each)
    const int g    = n0 + node;
    float s[8] = {};
    #pragma unroll
    for (int k = 0; k < K2c; ++k) {
        int pm = pmArr[node * K2c + k];
        int pc = pm >= 0 ? pm : 0;
        uint4 v = *(const uint4*)(h0B + (size_t)pc * 64 + cg * 8);
        float m = pm >= 0 ? 1.f : 0.f;
        const unsigned short* u = (const unsigned short*)&v;
        #pragma unroll
        for (int j = 0; j < 8; ++j) s[j] += m * b2f(u[j]);
    }
    const float ic  = invCnt[node];
    const float nz  = nc0[g & (F_F - 1)] * ns0[0];
    unsigned short outv[8];
    #pragma unroll
    for (int j = 0; j < 8; ++j) {
        float v = s[j] * ic + nz + b0[cg * 8 + j];
        outv[j] = f2b(actf(v));
    }
    *(uint4*)(haB + (size_t)g * 64 + cg * 8) = *(const uint4*)outv;
}

// ---------------- layer1: round-10 structure + depth-2 A-gather register prefetch ----------------
__global__ __launch_bounds__(256, 2)
void k_layer1(const unsigned short* __restrict__ haB,
              const int*  __restrict__ fn1,
              const int*  __restrict__ fip1,
              const unsigned short* __restrict__ wm1T,   // [b][k][o][64] bf16
              const float* __restrict__ nc1,
              const float* __restrict__ ns1,
              const float* __restrict__ b1,
              const float* __restrict__ stS,     // [2][64], already * 1/sqrt(64)
              const float* __restrict__ WtF,     // [3][64]
              float* __restrict__ hOut,
              float* __restrict__ yPre2)         // [N1][2][3]
{
    __shared__ unsigned short W_lds[9 * 4096];   // 73728 B, swizzled chunks
    const int tid  = threadIdx.x;
    const int g0   = blockIdx.x * 256;
    const int b    = g0 / F_F;
    const int wave = tid >> 6, lane = tid & 63;
    const int lg   = lane >> 4, lr = lane & 15;
    const int wbase = g0 + wave * 64;
    const unsigned short* wtap = wm1T + (size_t)b * K2c * 4096;

    // stage all 9 taps; logical 16B-chunk c of row stored at chunk (c ^ (row&7))
    #pragma unroll
    for (int t = 0; t < 18; ++t) {
        int idx = tid + 256 * t;
        int tap = idx >> 9;
        int rem = idx & 511;
        int row = rem >> 3, c = rem & 7;
        uint4 v = ((const uint4*)wtap)[idx];
        *(uint4*)(&W_lds[tap * 4096 + row * 64 + ((c ^ (row & 7)) << 3)]) = v;
    }

    int nbrk[4][9];
    #pragma unroll
    for (int rg = 0; rg < 4; ++rg) {
        int row = wbase + rg * 16 + lr;
        #pragma unroll
        for (int k = 0; k < 9; ++k) {
            int fn = fn1[(size_t)row * 9 + k];
            int ip = fip1[(size_t)row * 9 + k];
            nbrk[rg][k] = (!ip && fn < N1) ? fn : -1;
        }
    }

    // depth-2 prefetch: issue taps 0 and 1 (independent of LDS staging)
    uint4 pa[2][4][2];
    #pragma unroll
    for (int kk = 0; kk < 2; ++kk)
        #pragma unroll
        for (int rg = 0; rg < 4; ++rg) {
            int nbr = nbrk[rg][kk];
            int pc  = nbr >= 0 ? nbr : 0;
            const uint4* ap = (const uint4*)(haB + (size_t)pc * 64) + lg;
            pa[kk][rg][0] = ap[0];
            pa[kk][rg][1] = ap[4];
        }

    __syncthreads();     // the ONLY barrier

    f32x4 acc[4][4] = {};   // [rg][nt]
    #pragma unroll
    for (int kk = 0; kk < 9; ++kk) {
        const int slot = kk & 1;
        s16x8 bf[2][4];
        #pragma unroll
        for (int h = 0; h < 2; ++h)
            #pragma unroll
            for (int nt = 0; nt < 4; ++nt) {
                int row = nt * 16 + lr;
                bf[h][nt] = *(const s16x8*)(&W_lds[kk * 4096 + row * 64 + (((h * 4 + lg) ^ (row & 7)) << 3)]);
            }
        // pull current tap's fragments out of the prefetch slot
        uint4 cur[4][2];
        #pragma unroll
        for (int rg = 0; rg < 4; ++rg) {
            cur[rg][0] = pa[slot][rg][0];
            cur[rg][1] = pa[slot][rg][1];
        }
        // refill the slot with tap kk+2 (latency hides under this tap's MFMAs)
        if (kk + 2 < 9) {
            #pragma unroll
            for (int rg = 0; rg < 4; ++rg) {
                int nbr = nbrk[rg][kk + 2];
                int pc  = nbr >= 0 ? nbr : 0;
                const uint4* ap = (const uint4*)(haB + (size_t)pc * 64) + lg;
                pa[slot][rg][0] = ap[0];
                pa[slot][rg][1] = ap[4];
            }
        }
        #pragma unroll
        for (int rg = 0; rg < 4; ++rg) {
            int nbr = nbrk[rg][kk];
            uint4 a0 = cur[rg][0], a1 = cur[rg][1];
            if (nbr < 0) { a0 = uint4{0,0,0,0}; a1 = uint4{0,0,0,0}; }
            s16x8 af0 = *reinterpret_cast<const s16x8*>(&a0);
            s16x8 af1 = *reinterpret_cast<const s16x8*>(&a1);
            #pragma unroll
            for (int nt = 0; nt < 4; ++nt)
                acc[rg][nt] = __builtin_amdgcn_mfma_f32_16x16x32_bf16(af0, bf[0][nt], acc[rg][nt], 0, 0, 0);
            #pragma unroll
            for (int nt = 0; nt < 4; ++nt)
                acc[rg][nt] = __builtin_amdgcn_mfma_f32_16x16x32_bf16(af1, bf[1][nt], acc[rg][nt], 0, 0, 0);
        }
    }

    const float nsc = ns1[0];
    #pragma unroll
    for (int rg = 0; rg < 4; ++rg) {
        float p00[4] = {}, p01[4] = {}, p02[4] = {};
        float p10[4] = {}, p11[4] = {}, p12[4] = {};
        #pragma unroll
        for (int nt = 0; nt < 4; ++nt) {
            int o = nt * 16 + lr;
            float bias = b1[o];
            float st0  = stS[o], st1 = stS[64 + o];
            float wt0 = WtF[o], wt1 = WtF[64 + o], wt2 = WtF[128 + o];
            float w00 = wt0 * st0, w01 = wt1 * st0, w02 = wt2 * st0;
            float w10 = wt0 * st1, w11 = wt1 * st1, w12 = wt2 * st1;
            #pragma unroll
            for (int r = 0; r < 4; ++r) {
                int node = wbase + rg * 16 + lg * 4 + r;
                float v  = actf(acc[rg][nt][r] + nc1[node & (F_F - 1)] * nsc + bias);
                hOut[(size_t)node * 64 + o] = v;
                p00[r] += v * w00; p01[r] += v * w01; p02[r] += v * w02;
                p10[r] += v * w10; p11[r] += v * w11; p12[r] += v * w12;
            }
        }
        #pragma unroll
        for (int m = 1; m < 16; m <<= 1) {
            #pragma unroll
            for (int r = 0; r < 4; ++r) {
                p00[r] += __shfl_xor(p00[r], m, 64);
                p01[r] += __shfl_xor(p01[r], m, 64);
                p02[r] += __shfl_xor(p02[r], m, 64);
                p10[r] += __shfl_xor(p10[r], m, 64);
                p11[r] += __shfl_xor(p11[r], m, 64);
                p12[r] += __shfl_xor(p12[r], m, 64);
            }
        }
        if (lr == 0) {
            #pragma unroll
            for (int r = 0; r < 4; ++r) {
                int node = wbase + rg * 16 + lg * 4 + r;
                yPre2[(size_t)node * 6 + 0] = p00[r];
                yPre2[(size_t)node * 6 + 1] = p01[r];
                yPre2[(size_t)node * 6 + 2] = p02[r];
                yPre2[(size_t)node * 6 + 3] = p10[r];
                yPre2[(size_t)node * 6 + 4] = p11[r];
                yPre2[(size_t)node * 6 + 5] = p12[r];
            }
        }
    }
}

// ---------------- img upsample + yPre2 gather -> img (d_out tail) ----------------
__global__ __launch_bounds__(256)
void k_rgb(const float* __restrict__ yPre2,
           const float* __restrict__ imgF,
           const int*  __restrict__ fn1,
           const int*  __restrict__ fip1,
           const int*  __restrict__ pool,
           const float* __restrict__ btF,
           float* __restrict__ outImg)
{
    const int n = blockIdx.x * 256 + threadIdx.x;
    const int bOut = n / F_F;
    int fn[K2c], ip[K2c];
    #pragma unroll
    for (int k = 0; k < K2c; ++k) {
        fn[k] = fn1[(size_t)n * K2c + k];
        ip[k] = fip1[(size_t)n * K2c + k];
    }
    int pm[K2c], cnt = 0;
    #pragma unroll
    for (int k = 0; k < K2c; ++k) {
        int v  = !ip[k];
        cnt   += v;
        pm[k]  = (v && fn[k] < N1) ? pool[fn[k]] : -1;
    }
    float sr = 0.f, sg = 0.f, sb = 0.f;
    #pragma unroll
    for (int k = 0; k < K2c; ++k) {
        int   pc = pm[k] >= 0 ? pm[k] : 0;
        float m  = pm[k] >= 0 ? 1.f : 0.f;
        sr += m * imgF[(size_t)pc * 3 + 0];
        sg += m * imgF[(size_t)pc * 3 + 1];
        sb += m * imgF[(size_t)pc * 3 + 2];
    }
    int nb0 = (!ip[0] && fn[0] < N1) ? fn[0] : -1;
    float y0 = 0.f, y1 = 0.f, y2 = 0.f;
    if (nb0 >= 0) {
        const float* yp = yPre2 + (size_t)nb0 * 6 + bOut * 3;
        y0 = yp[0]; y1 = yp[1]; y2 = yp[2];
    }
    float ic = 1.f / (float)(cnt > 0 ? cnt : 1);
    y0 = fminf(fmaxf(y0 + btF[0], -256.f), 256.f);
    y1 = fminf(fmaxf(y1 + btF[1], -256.f), 256.f);
    y2 = fminf(fmaxf(y2 + btF[2], -256.f), 256.f);
    outImg[(size_t)n * 3 + 0] = sr * ic + y0;
    outImg[(size_t)n * 3 + 1] = sg * ic + y1;
    outImg[(size_t)n * 3 + 2] = sb * ic + y2;
}

// ---------------- host ----------------
extern "C" void kernel_launch(void* const* d_in, const int* in_sizes, int n_in,
                              void* d_out, int out_size, void* d_ws, size_t ws_size,
                              hipStream_t stream)
{
    const float* xF   = (const float*)d_in[0];
    const float* imgF = (const float*)d_in[1];
    const float* wsF  = (const float*)d_in[2];
    const float* a0w  = (const float*)d_in[3];
    const float* a0b  = (const float*)d_in[4];
    const float* W0w  = (const float*)d_in[5];
    const float* b0w  = (const float*)d_in[6];
    const float* ns0  = (const float*)d_in[7];
    const float* nc0  = (const float*)d_in[8];
    const float* a1w  = (const float*)d_in[9];
    const float* a1b  = (const float*)d_in[10];
    const float* W1w  = (const float*)d_in[11];
    const float* b1w  = (const float*)d_in[12];
    const float* ns1  = (const float*)d_in[13];
    const float* nc1  = (const float*)d_in[14];
    const float* atw  = (const float*)d_in[15];
    const float* atb  = (const float*)d_in[16];
    const float* WtF  = (const float*)d_in[17];
    const float* btF  = (const float*)d_in[18];
    const int* fn0  = (const int*)d_in[19];
    const int* fip0 = (const int*)d_in[20];
    const int* fn1  = (const int*)d_in[21];
    const int* fip1 = (const int*)d_in[22];
    const int* pool = (const int*)d_in[23];

    char* wsb = (char*)d_ws;
    float* fr = (float*)wsb;
    unsigned short* wm0T = (unsigned short*)(wsb + OFF_WM0T);
    unsigned short* wm1T = (unsigned short*)(wsb + OFF_WM1T);
    unsigned short* h0B  = (unsigned short*)(wsb + OFF_H0);
    unsigned short* haB  = (unsigned short*)(wsb + OFF_HA);
    unsigned short* xB   = (unsigned short*)(wsb + OFF_XB);   // overlays haB (dead until k_ha)
    float* yPre2         = (float*)(wsb + OFF_YPRE);          // overlays h0B (dead after k_ha)

    float* hOut   = (float*)d_out;
    float* imgOut = hOut + (size_t)N1 * 64;

    hipLaunchKernelGGL(k_styles, dim3(512), dim3(64), 0, stream,
                       wsF, a0w, a0b, a1w, a1b, atw, atb, fr);
    hipLaunchKernelGGL(k_wmod, dim3(256), dim3(256), 0, stream,
                       W0w, W1w, fr, wm0T, wm1T);
    hipLaunchKernelGGL(k_xcvt, dim3((N0 * C_IN) / 4 / 256), dim3(256), 0, stream,
                       xF, xB);
    hipLaunchKernelGGL(k_layer0, dim3(N0 / 256), dim3(256), 0, stream,
                       xB, fn0, fip0, wm0T, h0B);
    hipLaunchKernelGGL(k_ha, dim3(N1 / 32), dim3(256), 0, stream,
                       h0B, fn1, fip1, pool, nc0, ns0, b0w, haB);
    hipLaunchKernelGGL(k_layer1, dim3(N1 / 256), dim3(256), 0, stream,
                       haB, fn1, fip1, wm1T, nc1, ns1, b1w,
                       fr + FO_ST, WtF, hOut, yPre2);
    hipLaunchKernelGGL(k_rgb, dim3(N1 / 256), dim3(256), 0, stream,
                       yPre2, imgF, fn1, fip1, pool, btF, imgOut);
}

// Round 15
// 183.596 us; speedup vs baseline: 1.7218x; 1.0346x over previous
//
#include <hip/hip_runtime.h>
#include <hip/hip_bf16.h>

// ---------------- problem constants ----------------
constexpr int F_C   = 32768;
constexpr int F_F   = 131072;
constexpr int N0    = 65536;    // B*F_C
constexpr int N1    = 262144;   // B*F_F
constexpr int C_IN  = 128;
constexpr int W_DIM = 512;
constexpr int K2c   = 9;
constexpr float RS512     = 0.04419417382415922f;   // 1/sqrt(512)
constexpr float ACT_GAINc = 1.4142135623730951f;    // sqrt(2)

// ---------------- workspace layout ----------------
constexpr size_t FO_S0  = 0;
constexpr size_t FO_S1  = 256;
constexpr size_t FO_ST  = 384;
constexpr size_t OFF_WM0T = 2048;                    // [2][9][64 o][128 ci] u16 = 294912 B
constexpr size_t OFF_WM1T = OFF_WM0T + 294912;       // [2][9][64 o][64 ci] u16 = 147456 B
constexpr size_t OFF_H0   = 458752;                  // bf16 h0: 65536*64*2  = 8388608
constexpr size_t OFF_HA   = OFF_H0 + (size_t)8388608;// bf16 ha: 262144*64*2 = 33554432
// yPre2 (N1*6 f32) reuses the h0 region (h0B dead after k_ha).
constexpr size_t OFF_YPRE = OFF_H0;
// xB (bf16 copy of x) overlays the haB region (dead until k_ha runs).
constexpr size_t OFF_XB   = OFF_HA;

typedef short s16x8 __attribute__((ext_vector_type(8)));
typedef float f32x4 __attribute__((ext_vector_type(4)));

// ---------------- helpers ----------------
__device__ __forceinline__ float b2f(unsigned short u) {
    union { unsigned int i; float f; } v; v.i = ((unsigned int)u) << 16; return v.f;
}
__device__ __forceinline__ unsigned short f2b(float f) {
    __hip_bfloat16 h = __float2bfloat16(f);
    return *reinterpret_cast<unsigned short*>(&h);
}
__device__ __forceinline__ float waveRedSum(float v) {
    for (int m = 32; m; m >>= 1) v += __shfl_xor(v, m, 64);
    return v;
}
__device__ __forceinline__ float actf(float v) {
    float y = (v >= 0.f) ? v : 0.2f * v;
    y *= ACT_GAINc;
    return fminf(fmaxf(y, -256.f), 256.f);
}

// ---------------- styles ----------------
__global__ __launch_bounds__(64)
void k_styles(const float* __restrict__ wsF,
              const float* __restrict__ a0w, const float* __restrict__ a0b,
              const float* __restrict__ a1w, const float* __restrict__ a1b,
              const float* __restrict__ atw, const float* __restrict__ atb,
              float* __restrict__ fr)
{
    int bid = blockIdx.x, lane = threadIdx.x;
    int bb, ii, ll, row; const float *aw, *ab; float* dst; float post = 1.f;
    if (bid < 256)      { bb = bid >> 7;             ii = bid & 127; ll = 0; aw = a0w; ab = a0b; dst = fr + FO_S0; row = 128; }
    else if (bid < 384) { int t = bid - 256; bb = t >> 6; ii = t & 63; ll = 1; aw = a1w; ab = a1b; dst = fr + FO_S1; row = 64; }
    else                { int t = bid - 384; bb = t >> 6; ii = t & 63; ll = 2; aw = atw; ab = atb; dst = fr + FO_ST; row = 64; post = 0.125f; }
    const float* wsv = wsF + (size_t)(bb * 3 + ll) * W_DIM;
    const float* awr = aw + (size_t)ii * W_DIM;
    float s = 0.f;
    for (int j = lane; j < W_DIM; j += 64) s += wsv[j] * awr[j];
    s = waveRedSum(s);
    if (lane == 0) dst[bb * row + ii] = (s * RS512 + ab[ii]) * post;
}

// ---------------- demodulated weights -> wmodT[b][k][o][ci] (bf16) ----------------
__global__ __launch_bounds__(256)
void k_wmod(const float* __restrict__ W0,
            const float* __restrict__ W1,
            const float* __restrict__ fr,
            unsigned short* __restrict__ wm0T,
            unsigned short* __restrict__ wm1T)
{
    int bo = blockIdx.x, tid = threadIdx.x;
    int b, o, CI, NE; const float* W; const float* S; unsigned short* dst;
    if (bo < 128) { b = bo >> 6; o = bo & 63; CI = 128; NE = 1152; W = W0; S = fr + FO_S0; dst = wm0T; }
    else { int t = bo - 128; b = t >> 6; o = t & 63; CI = 64; NE = 576; W = W1; S = fr + FO_S1; dst = wm1T; }
    const float* Wo = W + (size_t)o * NE;
    const float* Sb = S + (size_t)b * CI;
    float ss = 0.f;
    for (int idx = tid; idx < NE; idx += 256) {
        int i = idx / K2c;
        float p = Wo[idx] * Sb[i];
        ss += p * p;
    }
    __shared__ float red[4];
    float s = waveRedSum(ss);
    if ((tid & 63) == 0) red[tid >> 6] = s;
    __syncthreads();
    float d = rsqrtf(red[0] + red[1] + red[2] + red[3] + 1e-8f);
    for (int idx = tid; idx < NE; idx += 256) {
        int i = idx / K2c, kk = idx - i * K2c;
        dst[((size_t)(b * K2c + kk) * 64 + o) * CI + i] = f2b(Wo[idx] * Sb[i] * d);
    }
}

// ---------------- x f32 -> bf16 copy (coalesced) ----------------
__global__ __launch_bounds__(256)
void k_xcvt(const float* __restrict__ xF, unsigned short* __restrict__ xB)
{
    int i = blockIdx.x * 256 + threadIdx.x;
    float4 f = ((const float4*)xF)[i];
    union { unsigned short u[4]; uint2 v; } t;
    t.u[0] = f2b(f.x); t.u[1] = f2b(f.y); t.u[2] = f2b(f.z); t.u[3] = f2b(f.w);
    ((uint2*)xB)[i] = t.v;
}

// ---------------- layer0: all-taps W LDS per K-half (72 KB, 2 blk/CU), A direct ----------------
__global__ __launch_bounds__(256, 2)
void k_layer0(const unsigned short* __restrict__ xB,
              const int*  __restrict__ fn0,
              const int*  __restrict__ fip0,
              const unsigned short* __restrict__ wm0T,   // [b][k][o][128] bf16
              unsigned short* __restrict__ h0B)
{
    __shared__ unsigned short W_lds[9 * 4096];   // 72 KB, one K-half of all 9 taps
    const int tid  = threadIdx.x;
    const int g0   = blockIdx.x * 256;
    const int b    = g0 / F_C;
    const int wave = tid >> 6, lane = tid & 63;
    const int lg   = lane >> 4, lr = lane & 15;
    const int wbase = g0 + wave * 64;
    const unsigned short* wtap = wm0T + (size_t)b * K2c * 64 * C_IN;

    int nbrk[4][9];
    #pragma unroll
    for (int rg = 0; rg < 4; ++rg) {
        int row = wbase + rg * 16 + lr;
        #pragma unroll
        for (int k = 0; k < 9; ++k) {
            int fn = fn0[(size_t)row * 9 + k];
            int ip = fip0[(size_t)row * 9 + k];
            nbrk[rg][k] = (!ip && fn < N0) ? fn : -1;
        }
    }

    f32x4 acc[4][4] = {};
    for (int h = 0; h < 2; ++h) {
        __syncthreads();     // h=1: ensure previous compute done before overwrite
        #pragma unroll
        for (int t = 0; t < 18; ++t) {               // 4608 chunks
            int idx = tid + 256 * t;
            int tap = idx >> 9;
            int rem = idx & 511;
            int row = rem >> 3, cc = rem & 7;        // 8 chunks per 64-ci row
            uint4 v = *(const uint4*)(wtap + ((size_t)tap * 64 + row) * C_IN + h * 64 + cc * 8);
            *(uint4*)(&W_lds[tap * 4096 + row * 64 + ((cc ^ (row & 7)) << 3)]) = v;
        }
        __syncthreads();
        #pragma unroll
        for (int kk = 0; kk < 9; ++kk) {
            s16x8 bf[2][4];
            #pragma unroll
            for (int c2 = 0; c2 < 2; ++c2)
                #pragma unroll
                for (int nt = 0; nt < 4; ++nt) {
                    int row = nt * 16 + lr;
                    bf[c2][nt] = *(const s16x8*)(&W_lds[kk * 4096 + row * 64 + (((c2 * 4 + lg) ^ (row & 7)) << 3)]);
                }
            #pragma unroll
            for (int rg = 0; rg < 4; ++rg) {
                int nbr = nbrk[rg][kk];
                int pc  = nbr >= 0 ? nbr : 0;
                const uint4* ap = (const uint4*)(xB + (size_t)pc * C_IN) + lg;
                uint4 a0 = ap[h * 8];                // k-chunk 0 of this half
                uint4 a1 = ap[h * 8 + 4];            // k-chunk 1
                if (nbr < 0) { a0 = uint4{0,0,0,0}; a1 = uint4{0,0,0,0}; }
                s16x8 af0 = *reinterpret_cast<const s16x8*>(&a0);
                s16x8 af1 = *reinterpret_cast<const s16x8*>(&a1);
                #pragma unroll
                for (int nt = 0; nt < 4; ++nt)
                    acc[rg][nt] = __builtin_amdgcn_mfma_f32_16x16x32_bf16(af0, bf[0][nt], acc[rg][nt], 0, 0, 0);
                #pragma unroll
                for (int nt = 0; nt < 4; ++nt)
                    acc[rg][nt] = __builtin_amdgcn_mfma_f32_16x16x32_bf16(af1, bf[1][nt], acc[rg][nt], 0, 0, 0);
            }
        }
    }
    #pragma unroll
    for (int rg = 0; rg < 4; ++rg)
        #pragma unroll
        for (int nt = 0; nt < 4; ++nt) {
            int o = nt * 16 + lr;
            #pragma unroll
            for (int r = 0; r < 4; ++r) {
                int node = wbase + rg * 16 + lg * 4 + r;
                h0B[(size_t)node * 64 + o] = f2b(acc[rg][nt][r]);
            }
        }
}

// ---------------- smooth upsample (h0 AND img) + noise + bias + act -> ha, imgUp ----------------
// thread = (node, 8-channel group) for the h0 part; threads 0..95 also compute
// the 3-channel img upsample using the SAME resolved pmArr/invCnt (img is
// L2-resident), writing the partial result directly into the output img tail.
__global__ __launch_bounds__(256)
void k_ha(const unsigned short* __restrict__ h0B,
          const int*  __restrict__ fn1,
          const int*  __restrict__ fip1,
          const int*  __restrict__ pool,
          const float* __restrict__ nc0,
          const float* __restrict__ ns0,
          const float* __restrict__ b0,
          const float* __restrict__ imgF,
          unsigned short* __restrict__ haB,
          float* __restrict__ outImg)
{
    __shared__ int   pmArr[288];
    __shared__ int   vArr[288];
    __shared__ float invCnt[32];
    const int tid = threadIdx.x;
    const int n0  = blockIdx.x * 32;
    for (int idx = tid; idx < 288; idx += 256) {
        int fn = fn1[(size_t)n0 * K2c + idx];
        int ip = fip1[(size_t)n0 * K2c + idx];
        int v  = !ip;
        int pm = -1;
        if (v && fn < N1) pm = pool[fn];
        pmArr[idx] = pm;
        vArr[idx]  = v;
    }
    __syncthreads();
    if (tid < 32) {
        int c = 0;
        #pragma unroll
        for (int k = 0; k < K2c; ++k) c += vArr[tid * K2c + k];
        invCnt[tid] = 1.f / (float)(c > 0 ? c : 1);
    }
    __syncthreads();
    // img upsample: 96 threads, one (node, channel) each
    if (tid < 96) {
        int node = tid / 3, c = tid - node * 3;
        float s = 0.f;
        #pragma unroll
        for (int k = 0; k < K2c; ++k) {
            int pm = pmArr[node * K2c + k];
            int pc = pm >= 0 ? pm : 0;
            float m = pm >= 0 ? 1.f : 0.f;
            s += m * imgF[(size_t)pc * 3 + c];
        }
        outImg[(size_t)(n0 + node) * 3 + c] = s * invCnt[node];
    }
    const int node = tid >> 3;      // 0..31
    const int cg   = tid & 7;       // 0..7  (8 channels each)
    const int g    = n0 + node;
    float s[8] = {};
    #pragma unroll
    for (int k = 0; k < K2c; ++k) {
        int pm = pmArr[node * K2c + k];
        int pc = pm >= 0 ? pm : 0;
        uint4 v = *(const uint4*)(h0B + (size_t)pc * 64 + cg * 8);
        float m = pm >= 0 ? 1.f : 0.f;
        const unsigned short* u = (const unsigned short*)&v;
        #pragma unroll
        for (int j = 0; j < 8; ++j) s[j] += m * b2f(u[j]);
    }
    const float ic  = invCnt[node];
    const float nz  = nc0[g & (F_F - 1)] * ns0[0];
    unsigned short outv[8];
    #pragma unroll
    for (int j = 0; j < 8; ++j) {
        float v = s[j] * ic + nz + b0[cg * 8 + j];
        outv[j] = f2b(actf(v));
    }
    *(uint4*)(haB + (size_t)g * 64 + cg * 8) = *(const uint4*)outv;
}

// ---------------- layer1: round-10 structure + depth-2 A-gather register prefetch ----------------
__global__ __launch_bounds__(256, 2)
void k_layer1(const unsigned short* __restrict__ haB,
              const int*  __restrict__ fn1,
              const int*  __restrict__ fip1,
              const unsigned short* __restrict__ wm1T,   // [b][k][o][64] bf16
              const float* __restrict__ nc1,
              const float* __restrict__ ns1,
              const float* __restrict__ b1,
              const float* __restrict__ stS,     // [2][64], already * 1/sqrt(64)
              const float* __restrict__ WtF,     // [3][64]
              float* __restrict__ hOut,
              float* __restrict__ yPre2)         // [N1][2][3]
{
    __shared__ unsigned short W_lds[9 * 4096];   // 73728 B, swizzled chunks
    const int tid  = threadIdx.x;
    const int g0   = blockIdx.x * 256;
    const int b    = g0 / F_F;
    const int wave = tid >> 6, lane = tid & 63;
    const int lg   = lane >> 4, lr = lane & 15;
    const int wbase = g0 + wave * 64;
    const unsigned short* wtap = wm1T + (size_t)b * K2c * 4096;

    // stage all 9 taps; logical 16B-chunk c of row stored at chunk (c ^ (row&7))
    #pragma unroll
    for (int t = 0; t < 18; ++t) {
        int idx = tid + 256 * t;
        int tap = idx >> 9;
        int rem = idx & 511;
        int row = rem >> 3, c = rem & 7;
        uint4 v = ((const uint4*)wtap)[idx];
        *(uint4*)(&W_lds[tap * 4096 + row * 64 + ((c ^ (row & 7)) << 3)]) = v;
    }

    int nbrk[4][9];
    #pragma unroll
    for (int rg = 0; rg < 4; ++rg) {
        int row = wbase + rg * 16 + lr;
        #pragma unroll
        for (int k = 0; k < 9; ++k) {
            int fn = fn1[(size_t)row * 9 + k];
            int ip = fip1[(size_t)row * 9 + k];
            nbrk[rg][k] = (!ip && fn < N1) ? fn : -1;
        }
    }

    // depth-2 prefetch: issue taps 0 and 1 (independent of LDS staging)
    uint4 pa[2][4][2];
    #pragma unroll
    for (int kk = 0; kk < 2; ++kk)
        #pragma unroll
        for (int rg = 0; rg < 4; ++rg) {
            int nbr = nbrk[rg][kk];
            int pc  = nbr >= 0 ? nbr : 0;
            const uint4* ap = (const uint4*)(haB + (size_t)pc * 64) + lg;
            pa[kk][rg][0] = ap[0];
            pa[kk][rg][1] = ap[4];
        }

    __syncthreads();     // the ONLY barrier

    f32x4 acc[4][4] = {};   // [rg][nt]
    #pragma unroll
    for (int kk = 0; kk < 9; ++kk) {
        const int slot = kk & 1;
        s16x8 bf[2][4];
        #pragma unroll
        for (int h = 0; h < 2; ++h)
            #pragma unroll
            for (int nt = 0; nt < 4; ++nt) {
                int row = nt * 16 + lr;
                bf[h][nt] = *(const s16x8*)(&W_lds[kk * 4096 + row * 64 + (((h * 4 + lg) ^ (row & 7)) << 3)]);
            }
        // pull current tap's fragments out of the prefetch slot
        uint4 cur[4][2];
        #pragma unroll
        for (int rg = 0; rg < 4; ++rg) {
            cur[rg][0] = pa[slot][rg][0];
            cur[rg][1] = pa[slot][rg][1];
        }
        // refill the slot with tap kk+2 (latency hides under this tap's MFMAs)
        if (kk + 2 < 9) {
            #pragma unroll
            for (int rg = 0; rg < 4; ++rg) {
                int nbr = nbrk[rg][kk + 2];
                int pc  = nbr >= 0 ? nbr : 0;
                const uint4* ap = (const uint4*)(haB + (size_t)pc * 64) + lg;
                pa[slot][rg][0] = ap[0];
                pa[slot][rg][1] = ap[4];
            }
        }
        #pragma unroll
        for (int rg = 0; rg < 4; ++rg) {
            int nbr = nbrk[rg][kk];
            uint4 a0 = cur[rg][0], a1 = cur[rg][1];
            if (nbr < 0) { a0 = uint4{0,0,0,0}; a1 = uint4{0,0,0,0}; }
            s16x8 af0 = *reinterpret_cast<const s16x8*>(&a0);
            s16x8 af1 = *reinterpret_cast<const s16x8*>(&a1);
            #pragma unroll
            for (int nt = 0; nt < 4; ++nt)
                acc[rg][nt] = __builtin_amdgcn_mfma_f32_16x16x32_bf16(af0, bf[0][nt], acc[rg][nt], 0, 0, 0);
            #pragma unroll
            for (int nt = 0; nt < 4; ++nt)
                acc[rg][nt] = __builtin_amdgcn_mfma_f32_16x16x32_bf16(af1, bf[1][nt], acc[rg][nt], 0, 0, 0);
        }
    }

    const float nsc = ns1[0];
    #pragma unroll
    for (int rg = 0; rg < 4; ++rg) {
        float p00[4] = {}, p01[4] = {}, p02[4] = {};
        float p10[4] = {}, p11[4] = {}, p12[4] = {};
        #pragma unroll
        for (int nt = 0; nt < 4; ++nt) {
            int o = nt * 16 + lr;
            float bias = b1[o];
            float st0  = stS[o], st1 = stS[64 + o];
            float wt0 = WtF[o], wt1 = WtF[64 + o], wt2 = WtF[128 + o];
            float w00 = wt0 * st0, w01 = wt1 * st0, w02 = wt2 * st0;
            float w10 = wt0 * st1, w11 = wt1 * st1, w12 = wt2 * st1;
            #pragma unroll
            for (int r = 0; r < 4; ++r) {
                int node = wbase + rg * 16 + lg * 4 + r;
                float v  = actf(acc[rg][nt][r] + nc1[node & (F_F - 1)] * nsc + bias);
                hOut[(size_t)node * 64 + o] = v;
                p00[r] += v * w00; p01[r] += v * w01; p02[r] += v * w02;
                p10[r] += v * w10; p11[r] += v * w11; p12[r] += v * w12;
            }
        }
        #pragma unroll
        for (int m = 1; m < 16; m <<= 1) {
            #pragma unroll
            for (int r = 0; r < 4; ++r) {
                p00[r] += __shfl_xor(p00[r], m, 64);
                p01[r] += __shfl_xor(p01[r], m, 64);
                p02[r] += __shfl_xor(p02[r], m, 64);
                p10[r] += __shfl_xor(p10[r], m, 64);
                p11[r] += __shfl_xor(p11[r], m, 64);
                p12[r] += __shfl_xor(p12[r], m, 64);
            }
        }
        if (lr == 0) {
            #pragma unroll
            for (int r = 0; r < 4; ++r) {
                int node = wbase + rg * 16 + lg * 4 + r;
                yPre2[(size_t)node * 6 + 0] = p00[r];
                yPre2[(size_t)node * 6 + 1] = p01[r];
                yPre2[(size_t)node * 6 + 2] = p02[r];
                yPre2[(size_t)node * 6 + 3] = p10[r];
                yPre2[(size_t)node * 6 + 4] = p11[r];
                yPre2[(size_t)node * 6 + 5] = p12[r];
            }
        }
    }
}

// ---------------- thin toRGB add: outImg[n] += clip(yPre2[nb0] + bt) ----------------
__global__ __launch_bounds__(256)
void k_rgb(const float* __restrict__ yPre2,
           const int*  __restrict__ fn1,
           const int*  __restrict__ fip1,
           const float* __restrict__ btF,
           float* __restrict__ outImg)
{
    const int n = blockIdx.x * 256 + threadIdx.x;
    const int bOut = n / F_F;
    int fn0 = fn1[(size_t)n * K2c];
    int ip0 = fip1[(size_t)n * K2c];
    int nb0 = (!ip0 && fn0 < N1) ? fn0 : -1;
    float y0 = 0.f, y1 = 0.f, y2 = 0.f;
    if (nb0 >= 0) {
        const float* yp = yPre2 + (size_t)nb0 * 6 + bOut * 3;
        y0 = yp[0]; y1 = yp[1]; y2 = yp[2];
    }
    y0 = fminf(fmaxf(y0 + btF[0], -256.f), 256.f);
    y1 = fminf(fmaxf(y1 + btF[1], -256.f), 256.f);
    y2 = fminf(fmaxf(y2 + btF[2], -256.f), 256.f);
    outImg[(size_t)n * 3 + 0] += y0;
    outImg[(size_t)n * 3 + 1] += y1;
    outImg[(size_t)n * 3 + 2] += y2;
}

// ---------------- host ----------------
extern "C" void kernel_launch(void* const* d_in, const int* in_sizes, int n_in,
                              void* d_out, int out_size, void* d_ws, size_t ws_size,
                              hipStream_t stream)
{
    const float* xF   = (const float*)d_in[0];
    const float* imgF = (const float*)d_in[1];
    const float* wsF  = (const float*)d_in[2];
    const float* a0w  = (const float*)d_in[3];
    const float* a0b  = (const float*)d_in[4];
    const float* W0w  = (const float*)d_in[5];
    const float* b0w  = (const float*)d_in[6];
    const float* ns0  = (const float*)d_in[7];
    const float* nc0  = (const float*)d_in[8];
    const float* a1w  = (const float*)d_in[9];
    const float* a1b  = (const float*)d_in[10];
    const float* W1w  = (const float*)d_in[11];
    const float* b1w  = (const float*)d_in[12];
    const float* ns1  = (const float*)d_in[13];
    const float* nc1  = (const float*)d_in[14];
    const float* atw  = (const float*)d_in[15];
    const float* atb  = (const float*)d_in[16];
    const float* WtF  = (const float*)d_in[17];
    const float* btF  = (const float*)d_in[18];
    const int* fn0  = (const int*)d_in[19];
    const int* fip0 = (const int*)d_in[20];
    const int* fn1  = (const int*)d_in[21];
    const int* fip1 = (const int*)d_in[22];
    const int* pool = (const int*)d_in[23];

    char* wsb = (char*)d_ws;
    float* fr = (float*)wsb;
    unsigned short* wm0T = (unsigned short*)(wsb + OFF_WM0T);
    unsigned short* wm1T = (unsigned short*)(wsb + OFF_WM1T);
    unsigned short* h0B  = (unsigned short*)(wsb + OFF_H0);
    unsigned short* haB  = (unsigned short*)(wsb + OFF_HA);
    unsigned short* xB   = (unsigned short*)(wsb + OFF_XB);   // overlays haB (dead until k_ha)
    float* yPre2         = (float*)(wsb + OFF_YPRE);          // overlays h0B (dead after k_ha)

    float* hOut   = (float*)d_out;
    float* imgOut = hOut + (size_t)N1 * 64;

    hipLaunchKernelGGL(k_styles, dim3(512), dim3(64), 0, stream,
                       wsF, a0w, a0b, a1w, a1b, atw, atb, fr);
    hipLaunchKernelGGL(k_wmod, dim3(256), dim3(256), 0, stream,
                       W0w, W1w, fr, wm0T, wm1T);
    hipLaunchKernelGGL(k_xcvt, dim3((N0 * C_IN) / 4 / 256), dim3(256), 0, stream,
                       xF, xB);
    hipLaunchKernelGGL(k_layer0, dim3(N0 / 256), dim3(256), 0, stream,
                       xB, fn0, fip0, wm0T, h0B);
    hipLaunchKernelGGL(k_ha, dim3(N1 / 32), dim3(256), 0, stream,
                       h0B, fn1, fip1, pool, nc0, ns0, b0w, imgF, haB, imgOut);
    hipLaunchKernelGGL(k_layer1, dim3(N1 / 256), dim3(256), 0, stream,
                       haB, fn1, fip1, wm1T, nc1, ns1, b1w,
                       fr + FO_ST, WtF, hOut, yPre2);
    hipLaunchKernelGGL(k_rgb, dim3(N1 / 256), dim3(256), 0, stream,
                       yPre2, fn1, fip1, btF, imgOut);
}